// Round 15
// baseline (157.643 us; speedup 1.0000x reference)
//
#include <hip/hip_runtime.h>

// MTH spiking-threshold recurrence: elementwise over N = B*C*H*W, T=4, K=8.
// x: [T+1, N] (plane 0 = bias). out: [T+1, N] (plane 0 = zeros).
//
// R8 structure: PERSISTENT waves (1024 blocks, grid-stride, 4 chunks/thread)
// with register double-buffer prefetch: issue chunk i+1's 5 loads, then
// compute+store chunk i, then roll. Load latency hides under compute+store;
// each wave keeps ~5-10 vmem ops in flight for its whole life (fill-kernel
// dynamics). Regular (L2 write-back) stores, NOT nontemporal: store
// completion in L2 is ~200cy, retirement never blocks the loop.
//
// Exactness (absmax 0):
//  - th == 1.0f path: thre[k]=2^-k, tt[k]=0.75*2^-k exact; same-sign IEEE
//    compares == integer compares on bit patterns -> integer threshold pick.
//  - spike/3 = (+-2^-k)/3 = 2^-k * RN(1/3) exact -> one multiply.
//  - d/3 via Markstein: q=RN(d*c); r=fma(-3,q,d) exact; fma(r,c,q) is the
//    correctly-rounded binary32 quotient -> bit-identical to IEEE div.
//  - mem update keeps reference association: (((mem+xt)-bias)+ein)-eout.

constexpr int T_STEPS = 4;
constexpr int K_THR   = 8;

typedef float f32x4 __attribute__((ext_vector_type(4)));

__device__ __forceinline__ float div3_cr(float v) {
    const float c = 1.0f / 3.0f;
    float q = v * c;
    float r = __builtin_fmaf(-3.0f, q, v);
    return __builtin_fmaf(r, c, q);
}

// spike for th == 1.0 exactly: integer threshold selection, bit-exact.
__device__ __forceinline__ float spike_fast(float m, float c) {
    const unsigned B075 = 0x3F400000u;   // bits(0.75f) = bits(tt[0])
    const unsigned B100 = 0x3F800000u;   // bits(1.0f)  = bits(thre[0])
    const float TT7 = 0.0058593750f;     // 0.75 * 2^-7
    const float TH7 = 0.0078125f;        // 2^-7

    const unsigned mb = (unsigned)__float_as_int(m);

    int dp = (int)(B075 - mb);
    int kp = (dp + 0x7FFFFF) >> 23;
    kp = kp < 0 ? 0 : kp;
    const float spv = __int_as_float((127 - kp) << 23);   // 2^-kp
    const float sp  = (m >= TT7) ? spv : 0.0f;

    int da = (int)(B075 - (mb & 0x7FFFFFFFu));
    int ka = (da + 0x7FFFFF) >> 23;
    ka = ka < 0 ? 0 : ka;
    int db = (int)(B100 - (unsigned)__float_as_int(c));
    int kb = (db + 0x7FFFFF) >> 23;
    kb = kb < 0 ? 0 : kb;
    const int kn = ka > kb ? ka : kb;
    const float snv = __int_as_float((127 - kn) << 23);   // 2^-kn
    const float sn  = (m <= -TT7 && c >= TH7) ? snv : 0.0f;

    return sp - sn;
}

__device__ __forceinline__ float spike_general(float m, float c, float th) {
    float sp = 0.f, sn = 0.f;
    #pragma unroll
    for (int k = K_THR - 1; k >= 0; --k) {
        const float thre = th * (1.0f / (float)(1 << k));
        const float tt   = 0.75f * thre;
        sp = (m >= tt) ? thre : sp;
        sn = (m <= -tt && c >= thre) ? thre : sn;
    }
    return sp - sn;
}

// compute the 4 spike planes for one float4 chunk
template <bool FAST>
__device__ __forceinline__ void compute_chunk(
    const f32x4& b4, const f32x4& x1, const f32x4& x2,
    const f32x4& x3, const f32x4& x4, float th,
    f32x4& s1, f32x4& s2, f32x4& s3, f32x4& s4)
{
    #pragma unroll
    for (int j = 0; j < 4; ++j) {
        const float b = b4[j];
        float mem = 0.f, cum = 0.f, ein = b, eout = 0.f;
        // t = 0 (denom 1)
        {
            const float xt = x1[j];
            float m = (((mem + xt) - b) + ein) - eout;
            float c = cum + eout;
            const float spike = FAST ? spike_fast(m, c) : spike_general(m, c, th);
            m -= spike; c += spike;
            ein += (xt - b); eout += spike;
            mem = m; cum = c; s1[j] = spike;
        }
        // t = 1 (denom 2 -> exact *0.5)
        {
            const float xt = x2[j];
            float m = (((mem + xt) - b) + ein) - eout;
            float c = cum + eout;
            const float spike = FAST ? spike_fast(m, c) : spike_general(m, c, th);
            m -= spike; c += spike;
            ein += (xt - b) * 0.5f; eout += spike * 0.5f;
            mem = m; cum = c; s2[j] = spike;
        }
        // t = 2 (denom 3 -> correctly-rounded)
        {
            const float xt = x3[j];
            float m = (((mem + xt) - b) + ein) - eout;
            float c = cum + eout;
            const float spike = FAST ? spike_fast(m, c) : spike_general(m, c, th);
            m -= spike; c += spike;
            ein += div3_cr(xt - b);
            eout += FAST ? (spike * (1.0f / 3.0f)) : div3_cr(spike);
            mem = m; cum = c; s3[j] = spike;
        }
        // t = 3 (denom 4); state after this is dead
        {
            const float xt = x4[j];
            float m = (((mem + xt) - b) + ein) - eout;
            float c = cum + eout;
            s4[j] = FAST ? spike_fast(m, c) : spike_general(m, c, th);
        }
    }
}

template <bool FAST>
__device__ __forceinline__ void run_loop(const f32x4* __restrict__ xv,
                                         f32x4* __restrict__ ov,
                                         float th, int n4, int i, int stride)
{
    // prime: loads for first chunk
    f32x4 b4 = xv[i];
    f32x4 x1 = xv[(size_t)1 * n4 + i];
    f32x4 x2 = xv[(size_t)2 * n4 + i];
    f32x4 x3 = xv[(size_t)3 * n4 + i];
    f32x4 x4 = xv[(size_t)4 * n4 + i];

    for (;;) {
        const int inext = i + stride;
        const bool more = inext < n4;

        // issue next chunk's loads BEFORE touching current data
        f32x4 nb, n1, n2, n3, n4v;
        if (more) {
            nb  = xv[inext];
            n1  = xv[(size_t)1 * n4 + inext];
            n2  = xv[(size_t)2 * n4 + inext];
            n3  = xv[(size_t)3 * n4 + inext];
            n4v = xv[(size_t)4 * n4 + inext];
        }

        // compute current chunk (waits only on current loads)
        f32x4 s1, s2, s3, s4;
        compute_chunk<FAST>(b4, x1, x2, x3, x4, th, s1, s2, s3, s4);

        // stores through L2 (write-back; fast completion)
        ov[i]                    = (f32x4){0.f, 0.f, 0.f, 0.f};
        ov[(size_t)1 * n4 + i]   = s1;
        ov[(size_t)2 * n4 + i]   = s2;
        ov[(size_t)3 * n4 + i]   = s3;
        ov[(size_t)4 * n4 + i]   = s4;

        if (!more) break;
        b4 = nb; x1 = n1; x2 = n2; x3 = n3; x4 = n4v;
        i = inext;
    }
}

__global__ __launch_bounds__(256) void mth_kernel(
    const float* __restrict__ x, const float* __restrict__ thresh,
    float* __restrict__ out, int n4)
{
    const float th = __uint_as_float(
        __builtin_amdgcn_readfirstlane(__float_as_uint(thresh[0])));

    const int stride = gridDim.x * 256;
    const int i = blockIdx.x * 256 + threadIdx.x;
    if (i >= n4) return;

    const f32x4* __restrict__ xv = reinterpret_cast<const f32x4*>(x);
    f32x4* __restrict__ ov       = reinterpret_cast<f32x4*>(out);

    if (th == 1.0f) run_loop<true >(xv, ov, th, n4, i, stride);
    else            run_loop<false>(xv, ov, th, n4, i, stride);
}

extern "C" void kernel_launch(void* const* d_in, const int* in_sizes, int n_in,
                              void* d_out, int out_size, void* d_ws, size_t ws_size,
                              hipStream_t stream)
{
    const float* x      = (const float*)d_in[0];
    const float* thresh = (const float*)d_in[1];
    float* out          = (float*)d_out;

    const int N  = in_sizes[0] / (T_STEPS + 1);  // 4,194,304
    const int n4 = N / 4;                         // 1,048,576

    // Persistent-ish grid: 1024 blocks = 4 blocks/CU resident, 4 chunks/thread.
    const int block = 256;
    const int grid  = 1024;
    mth_kernel<<<grid, block, 0, stream>>>(x, thresh, out, n4);
}